// Round 3
// baseline (1011.964 us; speedup 1.0000x reference)
//
#include <hip/hip_runtime.h>
#include <hip/hip_bf16.h>

typedef unsigned short u16;
typedef unsigned int u32;
typedef __attribute__((ext_vector_type(4))) float f32x4;
typedef __attribute__((ext_vector_type(8))) short bf16x8;

#define WLOOP (2.0f/3.0f - 1.0f)      /* -1/3 */
#define WEDGE (-(2.0f/3.0f))          /* -(2/lambda_max) */

__device__ __forceinline__ float bf2f(u16 h){ u32 u = ((u32)h)<<16; float f; __builtin_memcpy(&f,&u,4); return f; }
__device__ __forceinline__ u16 f2bf(float f){ u32 u; __builtin_memcpy(&u,&f,4); u32 r = u + 0x7fffu + ((u>>16)&1u); return (u16)(r>>16); }

__device__ __forceinline__ void async16(u16* lds, const u16* g){
  __builtin_amdgcn_global_load_lds((const __attribute__((address_space(1))) u32*)g,
                                   (__attribute__((address_space(3))) u32*)lds, 16, 0, 0);
}

// ---------------- graph prep ----------------
__global__ void k_hist(const int* __restrict__ ei, int E, int* cntf, int* cntb){
  int e = blockIdx.x*256 + threadIdx.x; if (e>=E) return;
  atomicAdd(&cntf[ei[e]],1); atomicAdd(&cntb[ei[E+e]],1);
}
__global__ void k_dinv(const int* __restrict__ cntf, float* dinv, int N){
  int n = blockIdx.x*256+threadIdx.x; if(n>=N) return;
  int d = cntf[n]; dinv[n] = d>0 ? rsqrtf((float)d) : 0.f;
}
__global__ void k_scanA(const int* __restrict__ cnt, int* excl, int* bsum, int n){
  __shared__ int sh[256]; int i = blockIdx.x*256+threadIdx.x;
  int v = (i<n)? cnt[i]:0; sh[threadIdx.x]=v; __syncthreads();
  for (int off=1; off<256; off<<=1){
    int t = (threadIdx.x>=off)? sh[threadIdx.x-off]:0; __syncthreads();
    sh[threadIdx.x]+=t; __syncthreads();
  }
  if (i<n) excl[i]=sh[threadIdx.x]-v;
  if (threadIdx.x==255) bsum[blockIdx.x]=sh[255];
}
__global__ void k_scanB(int* bsum, int nb, int* total){
  __shared__ int sh[512]; int t = threadIdx.x;
  int v = (t<nb)? bsum[t]:0; sh[t]=v; __syncthreads();
  for(int off=1; off<512; off<<=1){
    int a = (t>=off)? sh[t-off]:0; __syncthreads();
    sh[t]+=a; __syncthreads();
  }
  if (t<nb) bsum[t]=sh[t]-v;
  if (t==511) *total = sh[511];
}
__global__ void k_scanC(int* excl, const int* __restrict__ bsum, int n, int* cur){
  int i = blockIdx.x*256+threadIdx.x; if(i>=n) return;
  int v = excl[i]+bsum[blockIdx.x]; excl[i]=v; cur[i]=v;
}
__global__ void k_fill(const int* __restrict__ ei, int E, const float* __restrict__ dinv,
                       int* curf, int* curb, int* sf, float* wf, int* sb, float* wb){
  int e = blockIdx.x*256+threadIdx.x; if(e>=E) return;
  int r = ei[e], c = ei[E+e];
  float w = WEDGE * dinv[r]*dinv[c];
  int pf = atomicAdd(&curf[r],1); sf[pf]=c; wf[pf]=w;
  int pb = atomicAdd(&curb[c],1); sb[pb]=r; wb[pb]=w;
}

// ---------------- layer 1 (scalar cheb) ----------------
__global__ void k_sprop(const float* __restrict__ t1f, const float* __restrict__ t0f, float* df,
                        const float* __restrict__ t1b, const float* __restrict__ t0b, float* db,
                        const int* __restrict__ offf, const int* __restrict__ sfa, const float* __restrict__ wfa,
                        const int* __restrict__ offb, const int* __restrict__ sba, const float* __restrict__ wba,
                        int N){
  int i = blockIdx.x*256+threadIdx.x;
  int dir = 0; if (i >= N){ i -= N; dir = 1; }
  if (i >= N) return;
  const float* t1; const float* t0; float* d; const int* off; const int* s; const float* w;
  if (dir==0){ t1=t1f; t0=t0f; d=df; off=offf; s=sfa; w=wfa; }
  else       { t1=t1b; t0=t0b; d=db; off=offb; s=sba; w=wba; }
  float a = WLOOP * t1[i];
  int e1 = off[i+1];
  for (int e=off[i]; e<e1; ++e) a += w[e]*t1[s[e]];
  d[i] = t0 ? (2.f*a - t0[i]) : a;
}

__global__ void k_expand(const float* __restrict__ x,
   const float* __restrict__ cf1, const float* __restrict__ cf2, const float* __restrict__ cf3, const float* __restrict__ cf4,
   const float* __restrict__ cb1, const float* __restrict__ cb2, const float* __restrict__ cb3, const float* __restrict__ cb4,
   const float* __restrict__ W1f, const float* __restrict__ b1f,
   const float* __restrict__ W1b, const float* __restrict__ b1b,
   u16* __restrict__ T, int N){
  __shared__ float swf[640], swb[640], sbias[128];
  int tid = threadIdx.x;
  for (int i=tid;i<640;i+=256){ swf[i]=W1f[i]; swb[i]=W1b[i]; }
  if (tid<128) sbias[tid]=b1f[tid]+b1b[tid];
  __syncthreads();
  int j = tid & 127; int n = blockIdx.x*2 + (tid>>7);
  if (n>=N) return;
  float xx = x[n];
  float acc = sbias[j] + xx*(swf[j]+swb[j]);
  acc += cf1[n]*swf[128+j]; acc += cf2[n]*swf[256+j]; acc += cf3[n]*swf[384+j]; acc += cf4[n]*swf[512+j];
  acc += cb1[n]*swb[128+j]; acc += cb2[n]*swb[256+j]; acc += cb3[n]*swb[384+j]; acc += cb4[n]*swb[512+j];
  T[(size_t)n*1152 + j] = f2bf(fmaxf(acc,0.f));
}

// ---------------- layer 2 vector props (bf16 rows, fp32 accum) ----------------
__global__ void k_vprop(u16* __restrict__ T,
   const int* __restrict__ offf, const int* __restrict__ sfa, const float* __restrict__ wfa,
   const int* __restrict__ offb, const int* __restrict__ sba, const float* __restrict__ wba,
   int ssf, int dsf, int psf, int ssb, int dsb, int psb, int N){
  int gid = blockIdx.x*256 + threadIdx.x;
  int wid = gid>>6, l = threadIdx.x & 63;
  int dir = 0; if (wid >= N){ wid -= N; dir = 1; }
  if (wid >= N) return;
  const int* off; const int* s; const float* w; int ss,ds,ps;
  if (!dir){ off=offf;s=sfa;w=wfa;ss=ssf;ds=dsf;ps=psf; }
  else     { off=offb;s=sba;w=wba;ss=ssb;ds=dsb;ps=psb; }
  u32 u = *(const u32*)(T + ((size_t)wid*1152 + ss*128) + 2*l);
  float a0 = WLOOP*bf2f(u&0xffff), a1 = WLOOP*bf2f(u>>16);
  int e1 = off[wid+1];
  for (int e=off[wid]; e<e1; ++e){
    int sn = s[e]; float we = w[e];
    u32 ug = *(const u32*)(T + ((size_t)sn*1152 + ss*128) + 2*l);
    a0 += we*bf2f(ug&0xffff); a1 += we*bf2f(ug>>16);
  }
  float r0=a0, r1=a1;
  if (ps >= 0){
    u32 up = *(const u32*)(T + ((size_t)wid*1152 + ps*128) + 2*l);
    r0 = 2.f*a0 - bf2f(up&0xffff); r1 = 2.f*a1 - bf2f(up>>16);
  }
  *(u32*)(T + ((size_t)wid*1152 + ds*128) + 2*l) = ((u32)f2bf(r1)<<16) | (u32)f2bf(r0);
}

// ---------------- weight prep ----------------
__global__ void k_wprep(const float* __restrict__ W2f, const float* __restrict__ W2b,
                        const float* __restrict__ b2f, const float* __restrict__ b2b,
                        u16* __restrict__ Wt, float* __restrict__ bias2){
  int i = blockIdx.x*256+threadIdx.x;
  if (i < 512) bias2[i] = b2f[i]+b2b[i];
  if (i >= 512*1152) return;
  int j = i/1152, kc = i - j*1152;
  int s2 = kc>>7, c = kc&127;
  float v;
  if (s2==0)      v = W2f[c*512+j] + W2b[c*512+j];
  else if (s2<5)  v = W2f[(s2*128+c)*512 + j];
  else            v = W2b[((s2-4)*128+c)*512 + j];
  Wt[i] = f2bf(v);
}

// ---------------- pooled GEMM: T[M x 1152] @ Wt^T -> relu -> segment-sum ----------------
// 2-phase double-buffered pipeline (T3 minimum recipe): stage tile t+1, compute tile t,
// single __syncthreads per K-step (its implicit vmcnt(0) drains the prefetch AFTER compute).
__global__ __launch_bounds__(256) void k_gemm(const u16* __restrict__ T, const u16* __restrict__ Wt,
                        const float* __restrict__ bias2, const int* __restrict__ batch,
                        float* __restrict__ outp, int Mvalid){
  __shared__ u16 Al[2][128*64];
  __shared__ u16 Bl[2][128*64];
  int bid = blockIdx.x;
  int bn = bid & 3, bm = bid >> 2;
  int tid = threadIdx.x, w = tid>>6, l = tid&63;
  int wr = w>>1, wc = w&1;
  int hi = l>>4, lo = l&15;

  f32x4 acc[4][4];
  #pragma unroll
  for (int m=0;m<4;m++)
    #pragma unroll
    for (int n=0;n<4;n++){ acc[m][n][0]=0.f; acc[m][n][1]=0.f; acc[m][n][2]=0.f; acc[m][n][3]=0.f; }

  int ldsoff[4], gA[4], gB[4];
  #pragma unroll
  for (int i=0;i<4;i++){
    int r0 = (w*4+i)*8;
    int r  = r0 + (l>>3);
    int sc = (l&7) ^ (r&7);            // source chunk pre-swizzle (T2 / G4)
    ldsoff[i] = r0*64;
    gA[i] = (bm*128 + r)*1152 + sc*8;
    gB[i] = (bn*128 + r)*1152 + sc*8;
  }
  int rA[4], rB[4];
  #pragma unroll
  for (int m=0;m<4;m++){ rA[m] = wr*64 + m*16 + lo; rB[m] = wc*64 + m*16 + lo; }

  // prologue: stage tile 0 into buffer 0
  #pragma unroll
  for (int i=0;i<4;i++){
    async16(&Al[0][ldsoff[i]], T  + gA[i]);
    async16(&Bl[0][ldsoff[i]], Wt + gB[i]);
  }
  __syncthreads();                     // vmcnt(0): buf0 ready

  int cur = 0;
  for (int t=0; t<18; ++t){            // K = 1152 = 18 * 64
    if (t < 17){
      int kn = (t+1)*64;
      #pragma unroll
      for (int i=0;i<4;i++){
        async16(&Al[cur^1][ldsoff[i]], T  + gA[i] + kn);
        async16(&Bl[cur^1][ldsoff[i]], Wt + gB[i] + kn);
      }
    }
    const u16* Ab = Al[cur]; const u16* Bb = Bl[cur];
    #pragma unroll
    for (int ks=0; ks<2; ++ks){
      bf16x8 af[4], bfr[4];
      #pragma unroll
      for (int m=0;m<4;m++){
        int ch = (ks*4 + hi) ^ (rA[m]&7);
        af[m] = *(const bf16x8*)&Ab[rA[m]*64 + ch*8];
      }
      #pragma unroll
      for (int n=0;n<4;n++){
        int ch = (ks*4 + hi) ^ (rB[n]&7);
        bfr[n] = *(const bf16x8*)&Bb[rB[n]*64 + ch*8];
      }
      #pragma unroll
      for (int m=0;m<4;m++)
        #pragma unroll
        for (int n=0;n<4;n++)
          acc[m][n] = __builtin_amdgcn_mfma_f32_16x16x32_bf16(af[m], bfr[n], acc[m][n], 0, 0, 0);
    }
    __syncthreads();                   // drains prefetch (vmcnt 0) after compute; reads of buf[cur] done
    cur ^= 1;
  }

  // epilogue: bias + relu + segment-sum into pool (batch sorted -> run-length combine)
  #pragma unroll
  for (int m=0;m<4;m++){
    int rbase = bm*128 + wr*64 + m*16 + hi*4;
    #pragma unroll
    for (int n=0;n<4;n++){
      int col = bn*128 + wc*64 + n*16 + lo;
      float bc = bias2[col];
      f32x4 v = acc[m][n];
      int cur2 = -1; float ssum = 0.f;
      #pragma unroll
      for (int j2=0;j2<4;j2++){
        int row = rbase + j2;
        if (row < Mvalid){
          float val = fmaxf(v[j2] + bc, 0.f);
          int bg = batch[row];
          if (bg != cur2){ if (cur2 >= 0) atomicAdd(&outp[(cur2<<9) + col], ssum); cur2 = bg; ssum = 0.f; }
          ssum += val;
        }
      }
      if (cur2 >= 0) atomicAdd(&outp[(cur2<<9) + col], ssum);
    }
  }
}

// per-block LDS histogram: ~200 global atomics total instead of 100k
__global__ void k_count(const int* __restrict__ batch, int* cg, int N){
  __shared__ int sh[64];
  int t = threadIdx.x;
  if (t < 64) sh[t] = 0;
  __syncthreads();
  int base = blockIdx.x*1024;
  #pragma unroll
  for (int i = base + t; i < base + 1024; i += 256){
    if (i < N) atomicAdd(&sh[batch[i]], 1);
  }
  __syncthreads();
  if (t < 64){ int v = sh[t]; if (v) atomicAdd(&cg[t], v); }
}

__global__ void k_div(float* out, const int* __restrict__ cg, int total){
  int i = blockIdx.x*256+threadIdx.x; if (i>=total) return;
  int g = i>>9; out[i] /= fmaxf((float)cg[g], 1.f);
}

extern "C" void kernel_launch(void* const* d_in, const int* in_sizes, int n_in,
                              void* d_out, int out_size, void* d_ws, size_t ws_size,
                              hipStream_t stream) {
  const float* x   = (const float*)d_in[0];
  const int*   ei  = (const int*)d_in[1];
  const int*   bat = (const int*)d_in[2];
  const float* W1f = (const float*)d_in[3];
  const float* b1f = (const float*)d_in[4];
  const float* W1b = (const float*)d_in[5];
  const float* b1b = (const float*)d_in[6];
  const float* W2f = (const float*)d_in[7];
  const float* b2f = (const float*)d_in[8];
  const float* W2b = (const float*)d_in[9];
  const float* b2b = (const float*)d_in[10];

  const int N  = in_sizes[0];
  const int E  = in_sizes[1] / 2;
  const int NP = ((N + 127)/128)*128;

  // ---- ws layout ----
  size_t p = 0;
  auto A = [&](size_t sz){ size_t r = p; p += (sz + 255) & ~(size_t)255; return r; };
  size_t o_cnt  = A(2*(size_t)N*4);          // cnt_f | cnt_b
  size_t o_offf = A(((size_t)N+1)*4);
  size_t o_offb = A(((size_t)N+1)*4);
  size_t o_curf = A((size_t)N*4);
  size_t o_curb = A((size_t)N*4);
  size_t o_bsum = A(512*4);
  size_t o_dinv = A((size_t)N*4);
  size_t o_csf  = A((size_t)E*4);
  size_t o_cwf  = A((size_t)E*4);
  size_t o_csb  = A((size_t)E*4);
  size_t o_cwb  = A((size_t)E*4);
  size_t o_cf   = A(8*(size_t)N*4);          // cf1..4, cb1..4
  size_t o_Wt   = A((size_t)512*1152*2);
  size_t o_b2   = A(512*4);
  size_t o_cg   = A(64*4);
  size_t o_T    = A((size_t)NP*1152*2);
  if (p > ws_size) return;  // ws too small: bail (visible as validation failure)

  char* ws = (char*)d_ws;
  int*   cnt_f = (int*)(ws + o_cnt);
  int*   cnt_b = cnt_f + N;
  int*   off_f = (int*)(ws + o_offf);
  int*   off_b = (int*)(ws + o_offb);
  int*   cur_f = (int*)(ws + o_curf);
  int*   cur_b = (int*)(ws + o_curb);
  int*   bsum  = (int*)(ws + o_bsum);
  float* dinv  = (float*)(ws + o_dinv);
  int*   csf   = (int*)(ws + o_csf);
  float* cwf   = (float*)(ws + o_cwf);
  int*   csb   = (int*)(ws + o_csb);
  float* cwb   = (float*)(ws + o_cwb);
  float* cf1   = (float*)(ws + o_cf);
  float* cf2   = cf1 + N; float* cf3 = cf2 + N; float* cf4 = cf3 + N;
  float* cb1   = cf4 + N; float* cb2 = cb1 + N; float* cb3 = cb2 + N; float* cb4 = cb3 + N;
  u16*   Wt    = (u16*)(ws + o_Wt);
  float* bias2 = (float*)(ws + o_b2);
  int*   cg    = (int*)(ws + o_cg);
  u16*   T     = (u16*)(ws + o_T);
  float* outp  = (float*)d_out;

  const int nbN = (N + 255)/256;
  const int nbE = (E + 255)/256;
  const int nb2N = (2*N + 255)/256;

  // zero-init accumulators + T pad rows
  hipMemsetAsync(cnt_f, 0, 2*(size_t)N*4, stream);
  hipMemsetAsync(cg, 0, 64*4, stream);
  hipMemsetAsync(d_out, 0, (size_t)out_size*4, stream);
  if (NP > N) hipMemsetAsync(T + (size_t)N*1152, 0, (size_t)(NP-N)*1152*2, stream);

  // graph prep
  k_hist<<<nbE,256,0,stream>>>(ei, E, cnt_f, cnt_b);
  k_dinv<<<nbN,256,0,stream>>>(cnt_f, dinv, N);
  k_scanA<<<nbN,256,0,stream>>>(cnt_f, off_f, bsum, N);
  k_scanB<<<1,512,0,stream>>>(bsum, nbN, off_f + N);
  k_scanC<<<nbN,256,0,stream>>>(off_f, bsum, N, cur_f);
  k_scanA<<<nbN,256,0,stream>>>(cnt_b, off_b, bsum, N);
  k_scanB<<<1,512,0,stream>>>(bsum, nbN, off_b + N);
  k_scanC<<<nbN,256,0,stream>>>(off_b, bsum, N, cur_b);
  k_fill<<<nbE,256,0,stream>>>(ei, E, dinv, cur_f, cur_b, csf, cwf, csb, cwb);

  // layer 1 scalar chebyshev
  k_sprop<<<nb2N,256,0,stream>>>(x,   nullptr, cf1,  x,   nullptr, cb1, off_f,csf,cwf, off_b,csb,cwb, N);
  k_sprop<<<nb2N,256,0,stream>>>(cf1, x,       cf2,  cb1, x,       cb2, off_f,csf,cwf, off_b,csb,cwb, N);
  k_sprop<<<nb2N,256,0,stream>>>(cf2, cf1,     cf3,  cb2, cb1,     cb3, off_f,csf,cwf, off_b,csb,cwb, N);
  k_sprop<<<nb2N,256,0,stream>>>(cf3, cf2,     cf4,  cb3, cb2,     cb4, off_f,csf,cwf, off_b,csb,cwb, N);
  k_expand<<<(N+1)/2,256,0,stream>>>(x, cf1,cf2,cf3,cf4, cb1,cb2,cb3,cb4, W1f,b1f,W1b,b1b, T, N);

  // weights for fused GEMM
  k_wprep<<<(512*1152+255)/256,256,0,stream>>>(W2f, W2b, b2f, b2b, Wt, bias2);

  // layer 2 vector chebyshev: slots 0=h, 1..4=fwd, 5..8=bwd
  const int vb = (2*N*64 + 255)/256;
  k_vprop<<<vb,256,0,stream>>>(T, off_f,csf,cwf, off_b,csb,cwb, 0,1,-1, 0,5,-1, N);
  k_vprop<<<vb,256,0,stream>>>(T, off_f,csf,cwf, off_b,csb,cwb, 1,2, 0, 5,6, 0, N);
  k_vprop<<<vb,256,0,stream>>>(T, off_f,csf,cwf, off_b,csb,cwb, 2,3, 1, 6,7, 5, N);
  k_vprop<<<vb,256,0,stream>>>(T, off_f,csf,cwf, off_b,csb,cwb, 3,4, 2, 7,8, 6, N);

  // pooled GEMM + mean
  k_count<<<(N+1023)/1024,256,0,stream>>>(bat, cg, N);
  k_gemm<<<(NP/128)*4,256,0,stream>>>(T, Wt, bias2, bat, outp, N);
  k_div<<<(out_size+255)/256,256,0,stream>>>(outp, cg, out_size);
}

// Round 4
// 962.142 us; speedup vs baseline: 1.0518x; 1.0518x over previous
//
#include <hip/hip_runtime.h>
#include <hip/hip_bf16.h>

typedef unsigned short u16;
typedef unsigned int u32;
typedef __attribute__((ext_vector_type(4))) float f32x4;
typedef __attribute__((ext_vector_type(8))) short bf16x8;

#define WLOOP (2.0f/3.0f - 1.0f)      /* -1/3 */
#define WEDGE (-(2.0f/3.0f))          /* -(2/lambda_max) */

__device__ __forceinline__ float bf2f(u16 h){ u32 u = ((u32)h)<<16; float f; __builtin_memcpy(&f,&u,4); return f; }
__device__ __forceinline__ u16 f2bf(float f){ u32 u; __builtin_memcpy(&u,&f,4); u32 r = u + 0x7fffu + ((u>>16)&1u); return (u16)(r>>16); }

__device__ __forceinline__ void async16(u16* lds, const u16* g){
  __builtin_amdgcn_global_load_lds((const __attribute__((address_space(1))) u32*)g,
                                   (__attribute__((address_space(3))) u32*)lds, 16, 0, 0);
}

// ---------------- graph prep ----------------
__global__ void k_hist(const int* __restrict__ ei, int E, int* cntf, int* cntb){
  int e = blockIdx.x*256 + threadIdx.x; if (e>=E) return;
  atomicAdd(&cntf[ei[e]],1); atomicAdd(&cntb[ei[E+e]],1);
}
__global__ void k_dinv(const int* __restrict__ cntf, float* dinv, int N){
  int n = blockIdx.x*256+threadIdx.x; if(n>=N) return;
  int d = cntf[n]; dinv[n] = d>0 ? rsqrtf((float)d) : 0.f;
}
__global__ void k_scanA(const int* __restrict__ cnt, int* excl, int* bsum, int n){
  __shared__ int sh[256]; int i = blockIdx.x*256+threadIdx.x;
  int v = (i<n)? cnt[i]:0; sh[threadIdx.x]=v; __syncthreads();
  for (int off=1; off<256; off<<=1){
    int t = (threadIdx.x>=off)? sh[threadIdx.x-off]:0; __syncthreads();
    sh[threadIdx.x]+=t; __syncthreads();
  }
  if (i<n) excl[i]=sh[threadIdx.x]-v;
  if (threadIdx.x==255) bsum[blockIdx.x]=sh[255];
}
__global__ void k_scanB(int* bsum, int nb, int* total){
  __shared__ int sh[512]; int t = threadIdx.x;
  int v = (t<nb)? bsum[t]:0; sh[t]=v; __syncthreads();
  for(int off=1; off<512; off<<=1){
    int a = (t>=off)? sh[t-off]:0; __syncthreads();
    sh[t]+=a; __syncthreads();
  }
  if (t<nb) bsum[t]=sh[t]-v;
  if (t==511) *total = sh[511];
}
__global__ void k_scanC(int* excl, const int* __restrict__ bsum, int n, int* cur){
  int i = blockIdx.x*256+threadIdx.x; if(i>=n) return;
  int v = excl[i]+bsum[blockIdx.x]; excl[i]=v; cur[i]=v;
}
__global__ void k_fill(const int* __restrict__ ei, int E, const float* __restrict__ dinv,
                       int* curf, int* curb, int* sf, float* wf, int* sb, float* wb){
  int e = blockIdx.x*256+threadIdx.x; if(e>=E) return;
  int r = ei[e], c = ei[E+e];
  float w = WEDGE * dinv[r]*dinv[c];
  int pf = atomicAdd(&curf[r],1); sf[pf]=c; wf[pf]=w;
  int pb = atomicAdd(&curb[c],1); sb[pb]=r; wb[pb]=w;
}

// ---------------- layer 1 (scalar cheb) ----------------
__global__ void k_sprop(const float* __restrict__ t1f, const float* __restrict__ t0f, float* df,
                        const float* __restrict__ t1b, const float* __restrict__ t0b, float* db,
                        const int* __restrict__ offf, const int* __restrict__ sfa, const float* __restrict__ wfa,
                        const int* __restrict__ offb, const int* __restrict__ sba, const float* __restrict__ wba,
                        int N){
  int i = blockIdx.x*256+threadIdx.x;
  int dir = 0; if (i >= N){ i -= N; dir = 1; }
  if (i >= N) return;
  const float* t1; const float* t0; float* d; const int* off; const int* s; const float* w;
  if (dir==0){ t1=t1f; t0=t0f; d=df; off=offf; s=sfa; w=wfa; }
  else       { t1=t1b; t0=t0b; d=db; off=offb; s=sba; w=wba; }
  float a = WLOOP * t1[i];
  int e1 = off[i+1];
  for (int e=off[i]; e<e1; ++e) a += w[e]*t1[s[e]];
  d[i] = t0 ? (2.f*a - t0[i]) : a;
}

__global__ void k_expand(const float* __restrict__ x,
   const float* __restrict__ cf1, const float* __restrict__ cf2, const float* __restrict__ cf3, const float* __restrict__ cf4,
   const float* __restrict__ cb1, const float* __restrict__ cb2, const float* __restrict__ cb3, const float* __restrict__ cb4,
   const float* __restrict__ W1f, const float* __restrict__ b1f,
   const float* __restrict__ W1b, const float* __restrict__ b1b,
   u16* __restrict__ T, int N){
  __shared__ float swf[640], swb[640], sbias[128];
  int tid = threadIdx.x;
  for (int i=tid;i<640;i+=256){ swf[i]=W1f[i]; swb[i]=W1b[i]; }
  if (tid<128) sbias[tid]=b1f[tid]+b1b[tid];
  __syncthreads();
  int j = tid & 127; int n = blockIdx.x*2 + (tid>>7);
  if (n>=N) return;
  float xx = x[n];
  float acc = sbias[j] + xx*(swf[j]+swb[j]);
  acc += cf1[n]*swf[128+j]; acc += cf2[n]*swf[256+j]; acc += cf3[n]*swf[384+j]; acc += cf4[n]*swf[512+j];
  acc += cb1[n]*swb[128+j]; acc += cb2[n]*swb[256+j]; acc += cb3[n]*swb[384+j]; acc += cb4[n]*swb[512+j];
  T[(size_t)n*1152 + j] = f2bf(fmaxf(acc,0.f));
}

// ---------------- layer 2 vector props (bf16 rows, fp32 accum) ----------------
__global__ void k_vprop(u16* __restrict__ T,
   const int* __restrict__ offf, const int* __restrict__ sfa, const float* __restrict__ wfa,
   const int* __restrict__ offb, const int* __restrict__ sba, const float* __restrict__ wba,
   int ssf, int dsf, int psf, int ssb, int dsb, int psb, int N){
  int gid = blockIdx.x*256 + threadIdx.x;
  int wid = gid>>6, l = threadIdx.x & 63;
  int dir = 0; if (wid >= N){ wid -= N; dir = 1; }
  if (wid >= N) return;
  const int* off; const int* s; const float* w; int ss,ds,ps;
  if (!dir){ off=offf;s=sfa;w=wfa;ss=ssf;ds=dsf;ps=psf; }
  else     { off=offb;s=sba;w=wba;ss=ssb;ds=dsb;ps=psb; }
  u32 u = *(const u32*)(T + ((size_t)wid*1152 + ss*128) + 2*l);
  float a0 = WLOOP*bf2f(u&0xffff), a1 = WLOOP*bf2f(u>>16);
  int e1 = off[wid+1];
  for (int e=off[wid]; e<e1; ++e){
    int sn = s[e]; float we = w[e];
    u32 ug = *(const u32*)(T + ((size_t)sn*1152 + ss*128) + 2*l);
    a0 += we*bf2f(ug&0xffff); a1 += we*bf2f(ug>>16);
  }
  float r0=a0, r1=a1;
  if (ps >= 0){
    u32 up = *(const u32*)(T + ((size_t)wid*1152 + ps*128) + 2*l);
    r0 = 2.f*a0 - bf2f(up&0xffff); r1 = 2.f*a1 - bf2f(up>>16);
  }
  *(u32*)(T + ((size_t)wid*1152 + ds*128) + 2*l) = ((u32)f2bf(r1)<<16) | (u32)f2bf(r0);
}

// ---------------- weight prep ----------------
__global__ void k_wprep(const float* __restrict__ W2f, const float* __restrict__ W2b,
                        const float* __restrict__ b2f, const float* __restrict__ b2b,
                        u16* __restrict__ Wt, float* __restrict__ bias2){
  int i = blockIdx.x*256+threadIdx.x;
  if (i < 512) bias2[i] = b2f[i]+b2b[i];
  if (i >= 512*1152) return;
  int j = i/1152, kc = i - j*1152;
  int s2 = kc>>7, c = kc&127;
  float v;
  if (s2==0)      v = W2f[c*512+j] + W2b[c*512+j];
  else if (s2<5)  v = W2f[(s2*128+c)*512 + j];
  else            v = W2b[((s2-4)*128+c)*512 + j];
  Wt[i] = f2bf(v);
}

// ---------------- pooled GEMM: T[M x 1152] @ Wt^T -> relu -> segment-sum ----------------
// BM=128, BN=512 (A read once), BK=32, 8 waves, chunk-major LDS (conflict-free),
// raw s_barrier x2 per K-step + counted vmcnt(5) (T3/T4), setprio around MFMA (T5).
__global__ __launch_bounds__(512, 2) void k_gemm(const u16* __restrict__ T, const u16* __restrict__ Wt,
                        const float* __restrict__ bias2, const int* __restrict__ batch,
                        float* __restrict__ outp, int Mvalid){
  // chunk-major: chunk c holds k-range [c*8, c*8+8) for all rows.
  __shared__ u16 Al[2][4*128*8];    // 4 chunks x 128 rows x 8 u16 = 8KB per buf
  __shared__ u16 Bl[2][4*512*8];    // 4 chunks x 512 rows x 8 u16 = 32KB per buf
  int bm = blockIdx.x;
  int tid = threadIdx.x, w = tid>>6, l = tid&63;
  int wr = w>>2, wc = w&3;          // wave grid 2 x 4 -> per-wave 64 rows x 128 cols
  int hi = l>>4, lo = l&15;

  f32x4 acc[4][8];
  #pragma unroll
  for (int m=0;m<4;m++)
    #pragma unroll
    for (int n=0;n<8;n++){ acc[m][n][0]=0.f; acc[m][n][1]=0.f; acc[m][n][2]=0.f; acc[m][n][3]=0.f; }

  // staging addresses
  int ar = tid & 127, ach = tid >> 7;                       // A: row, chunk
  const u16* asrc = T + (size_t)(bm*128 + ar)*1152 + ach*8; // + kk
  const u16* bsrc = Wt + (size_t)tid*1152;                  // + kk + i*8
  const int adst = w*512;                                   // u16 idx, wave-uniform
  // fragment read bases (u16 idx)
  const int aoff = (wr*64 + lo)*8 + hi*1024;                // + m*128
  const int boff = (wc*128 + lo)*8 + hi*4096;               // + n*128

  #define STAGE(buf, kk) do { \
    async16(&Al[buf][adst], asrc + (kk)); \
    _Pragma("unroll") \
    for (int i_=0;i_<4;i_++) async16(&Bl[buf][i_*4096 + adst], bsrc + (kk) + i_*8); \
  } while(0)

  STAGE(0, 0);
  for (int t=0; t<36; ++t){                                 // K = 1152 = 36*32
    int cur = t & 1;
    if (t < 35){
      STAGE(cur^1, (t+1)*32);
      asm volatile("s_waitcnt vmcnt(5)" ::: "memory");      // stage(t) complete, stage(t+1) in flight
    } else {
      asm volatile("s_waitcnt vmcnt(0)" ::: "memory");
    }
    asm volatile("s_barrier" ::: "memory");                 // tile t resident for all waves
    const u16* Ab = Al[cur]; const u16* Bb = Bl[cur];
    bf16x8 af[4], bfr[8];
    #pragma unroll
    for (int m=0;m<4;m++) af[m] = *(const bf16x8*)&Ab[aoff + m*128];
    #pragma unroll
    for (int n=0;n<8;n++) bfr[n] = *(const bf16x8*)&Bb[boff + n*128];
    __builtin_amdgcn_s_setprio(1);
    #pragma unroll
    for (int m=0;m<4;m++)
      #pragma unroll
      for (int n=0;n<8;n++)
        acc[m][n] = __builtin_amdgcn_mfma_f32_16x16x32_bf16(af[m], bfr[n], acc[m][n], 0, 0, 0);
    __builtin_amdgcn_s_setprio(0);
    asm volatile("s_barrier" ::: "memory");                 // reads done -> next stage may overwrite
  }
  #undef STAGE

  // epilogue: bias + relu + pooled segment-sum (batch sorted -> run-length over 16 rows)
  int bg[16];
  #pragma unroll
  for (int m=0;m<4;m++)
    #pragma unroll
    for (int j2=0;j2<4;j2++){
      int row = bm*128 + wr*64 + m*16 + hi*4 + j2;
      bg[m*4+j2] = (row < Mvalid) ? batch[row] : -1;
    }
  #pragma unroll
  for (int n=0;n<8;n++){
    int col = wc*128 + n*16 + lo;
    float bc = bias2[col];
    int cg2 = -1; float ssum = 0.f;
    #pragma unroll
    for (int idx=0; idx<16; idx++){
      int g = bg[idx];
      if (g >= 0){
        float val = fmaxf(acc[idx>>2][n][idx&3] + bc, 0.f);
        if (g != cg2){ if (cg2 >= 0) atomicAdd(&outp[(cg2<<9) + col], ssum); cg2 = g; ssum = 0.f; }
        ssum += val;
      }
    }
    if (cg2 >= 0) atomicAdd(&outp[(cg2<<9) + col], ssum);
  }
}

// per-block LDS histogram: ~200 global atomics total instead of 100k
__global__ void k_count(const int* __restrict__ batch, int* cg, int N){
  __shared__ int sh[64];
  int t = threadIdx.x;
  if (t < 64) sh[t] = 0;
  __syncthreads();
  int base = blockIdx.x*1024;
  #pragma unroll
  for (int i = base + t; i < base + 1024; i += 256){
    if (i < N) atomicAdd(&sh[batch[i]], 1);
  }
  __syncthreads();
  if (t < 64){ int v = sh[t]; if (v) atomicAdd(&cg[t], v); }
}

__global__ void k_div(float* out, const int* __restrict__ cg, int total){
  int i = blockIdx.x*256+threadIdx.x; if (i>=total) return;
  int g = i>>9; out[i] /= fmaxf((float)cg[g], 1.f);
}

extern "C" void kernel_launch(void* const* d_in, const int* in_sizes, int n_in,
                              void* d_out, int out_size, void* d_ws, size_t ws_size,
                              hipStream_t stream) {
  const float* x   = (const float*)d_in[0];
  const int*   ei  = (const int*)d_in[1];
  const int*   bat = (const int*)d_in[2];
  const float* W1f = (const float*)d_in[3];
  const float* b1f = (const float*)d_in[4];
  const float* W1b = (const float*)d_in[5];
  const float* b1b = (const float*)d_in[6];
  const float* W2f = (const float*)d_in[7];
  const float* b2f = (const float*)d_in[8];
  const float* W2b = (const float*)d_in[9];
  const float* b2b = (const float*)d_in[10];

  const int N  = in_sizes[0];
  const int E  = in_sizes[1] / 2;
  const int NP = ((N + 127)/128)*128;

  // ---- ws layout ----
  size_t p = 0;
  auto A = [&](size_t sz){ size_t r = p; p += (sz + 255) & ~(size_t)255; return r; };
  size_t o_cnt  = A(2*(size_t)N*4);          // cnt_f | cnt_b
  size_t o_offf = A(((size_t)N+1)*4);
  size_t o_offb = A(((size_t)N+1)*4);
  size_t o_curf = A((size_t)N*4);
  size_t o_curb = A((size_t)N*4);
  size_t o_bsum = A(512*4);
  size_t o_dinv = A((size_t)N*4);
  size_t o_csf  = A((size_t)E*4);
  size_t o_cwf  = A((size_t)E*4);
  size_t o_csb  = A((size_t)E*4);
  size_t o_cwb  = A((size_t)E*4);
  size_t o_cf   = A(8*(size_t)N*4);          // cf1..4, cb1..4
  size_t o_Wt   = A((size_t)512*1152*2);
  size_t o_b2   = A(512*4);
  size_t o_cg   = A(64*4);
  size_t o_T    = A((size_t)NP*1152*2);
  if (p > ws_size) return;  // ws too small: bail (visible as validation failure)

  char* ws = (char*)d_ws;
  int*   cnt_f = (int*)(ws + o_cnt);
  int*   cnt_b = cnt_f + N;
  int*   off_f = (int*)(ws + o_offf);
  int*   off_b = (int*)(ws + o_offb);
  int*   cur_f = (int*)(ws + o_curf);
  int*   cur_b = (int*)(ws + o_curb);
  int*   bsum  = (int*)(ws + o_bsum);
  float* dinv  = (float*)(ws + o_dinv);
  int*   csf   = (int*)(ws + o_csf);
  float* cwf   = (float*)(ws + o_cwf);
  int*   csb   = (int*)(ws + o_csb);
  float* cwb   = (float*)(ws + o_cwb);
  float* cf1   = (float*)(ws + o_cf);
  float* cf2   = cf1 + N; float* cf3 = cf2 + N; float* cf4 = cf3 + N;
  float* cb1   = cf4 + N; float* cb2 = cb1 + N; float* cb3 = cb2 + N; float* cb4 = cb3 + N;
  u16*   Wt    = (u16*)(ws + o_Wt);
  float* bias2 = (float*)(ws + o_b2);
  int*   cg    = (int*)(ws + o_cg);
  u16*   T     = (u16*)(ws + o_T);
  float* outp  = (float*)d_out;

  const int nbN = (N + 255)/256;
  const int nbE = (E + 255)/256;
  const int nb2N = (2*N + 255)/256;

  // zero-init accumulators + T pad rows
  hipMemsetAsync(cnt_f, 0, 2*(size_t)N*4, stream);
  hipMemsetAsync(cg, 0, 64*4, stream);
  hipMemsetAsync(d_out, 0, (size_t)out_size*4, stream);
  if (NP > N) hipMemsetAsync(T + (size_t)N*1152, 0, (size_t)(NP-N)*1152*2, stream);

  // graph prep
  k_hist<<<nbE,256,0,stream>>>(ei, E, cnt_f, cnt_b);
  k_dinv<<<nbN,256,0,stream>>>(cnt_f, dinv, N);
  k_scanA<<<nbN,256,0,stream>>>(cnt_f, off_f, bsum, N);
  k_scanB<<<1,512,0,stream>>>(bsum, nbN, off_f + N);
  k_scanC<<<nbN,256,0,stream>>>(off_f, bsum, N, cur_f);
  k_scanA<<<nbN,256,0,stream>>>(cnt_b, off_b, bsum, N);
  k_scanB<<<1,512,0,stream>>>(bsum, nbN, off_b + N);
  k_scanC<<<nbN,256,0,stream>>>(off_b, bsum, N, cur_b);
  k_fill<<<nbE,256,0,stream>>>(ei, E, dinv, cur_f, cur_b, csf, cwf, csb, cwb);

  // layer 1 scalar chebyshev
  k_sprop<<<nb2N,256,0,stream>>>(x,   nullptr, cf1,  x,   nullptr, cb1, off_f,csf,cwf, off_b,csb,cwb, N);
  k_sprop<<<nb2N,256,0,stream>>>(cf1, x,       cf2,  cb1, x,       cb2, off_f,csf,cwf, off_b,csb,cwb, N);
  k_sprop<<<nb2N,256,0,stream>>>(cf2, cf1,     cf3,  cb2, cb1,     cb3, off_f,csf,cwf, off_b,csb,cwb, N);
  k_sprop<<<nb2N,256,0,stream>>>(cf3, cf2,     cf4,  cb3, cb2,     cb4, off_f,csf,cwf, off_b,csb,cwb, N);
  k_expand<<<(N+1)/2,256,0,stream>>>(x, cf1,cf2,cf3,cf4, cb1,cb2,cb3,cb4, W1f,b1f,W1b,b1b, T, N);

  // weights for fused GEMM
  k_wprep<<<(512*1152+255)/256,256,0,stream>>>(W2f, W2b, b2f, b2b, Wt, bias2);

  // layer 2 vector chebyshev: slots 0=h, 1..4=fwd, 5..8=bwd
  const int vb = (2*N*64 + 255)/256;
  k_vprop<<<vb,256,0,stream>>>(T, off_f,csf,cwf, off_b,csb,cwb, 0,1,-1, 0,5,-1, N);
  k_vprop<<<vb,256,0,stream>>>(T, off_f,csf,cwf, off_b,csb,cwb, 1,2, 0, 5,6, 0, N);
  k_vprop<<<vb,256,0,stream>>>(T, off_f,csf,cwf, off_b,csb,cwb, 2,3, 1, 6,7, 5, N);
  k_vprop<<<vb,256,0,stream>>>(T, off_f,csf,cwf, off_b,csb,cwb, 3,4, 2, 7,8, 6, N);

  // pooled GEMM + mean
  k_count<<<(N+1023)/1024,256,0,stream>>>(bat, cg, N);
  k_gemm<<<NP/128,512,0,stream>>>(T, Wt, bias2, bat, outp, N);
  k_div<<<(out_size+255)/256,256,0,stream>>>(outp, cg, out_size);
}

// Round 5
// 846.455 us; speedup vs baseline: 1.1955x; 1.1367x over previous
//
#include <hip/hip_runtime.h>
#include <hip/hip_bf16.h>

typedef unsigned short u16;
typedef unsigned int u32;
typedef __attribute__((ext_vector_type(4))) float f32x4;
typedef __attribute__((ext_vector_type(8))) short bf16x8;

#define WLOOP (2.0f/3.0f - 1.0f)      /* -1/3 */
#define WEDGE (-(2.0f/3.0f))          /* -(2/lambda_max) */

__device__ __forceinline__ float bf2f(u16 h){ u32 u = ((u32)h)<<16; float f; __builtin_memcpy(&f,&u,4); return f; }
__device__ __forceinline__ u16 f2bf(float f){ u32 u; __builtin_memcpy(&u,&f,4); u32 r = u + 0x7fffu + ((u>>16)&1u); return (u16)(r>>16); }

__device__ __forceinline__ void async16(u16* lds, const u16* g){
  __builtin_amdgcn_global_load_lds((const __attribute__((address_space(1))) u32*)g,
                                   (__attribute__((address_space(3))) u32*)lds, 16, 0, 0);
}

// ---------------- graph prep ----------------
__global__ void k_hist(const int* __restrict__ ei, int E, int* cntf, int* cntb){
  int e = blockIdx.x*256 + threadIdx.x; if (e>=E) return;
  atomicAdd(&cntf[ei[e]],1); atomicAdd(&cntb[ei[E+e]],1);
}
__global__ void k_dinv(const int* __restrict__ cntf, float* dinv, int N){
  int n = blockIdx.x*256+threadIdx.x; if(n>=N) return;
  int d = cntf[n]; dinv[n] = d>0 ? rsqrtf((float)d) : 0.f;
}
__global__ void k_scanA(const int* __restrict__ cnt, int* excl, int* bsum, int n){
  __shared__ int sh[256]; int i = blockIdx.x*256+threadIdx.x;
  int v = (i<n)? cnt[i]:0; sh[threadIdx.x]=v; __syncthreads();
  for (int off=1; off<256; off<<=1){
    int t = (threadIdx.x>=off)? sh[threadIdx.x-off]:0; __syncthreads();
    sh[threadIdx.x]+=t; __syncthreads();
  }
  if (i<n) excl[i]=sh[threadIdx.x]-v;
  if (threadIdx.x==255) bsum[blockIdx.x]=sh[255];
}
__global__ void k_scanB(int* bsum, int nb, int* total){
  __shared__ int sh[512]; int t = threadIdx.x;
  int v = (t<nb)? bsum[t]:0; sh[t]=v; __syncthreads();
  for(int off=1; off<512; off<<=1){
    int a = (t>=off)? sh[t-off]:0; __syncthreads();
    sh[t]+=a; __syncthreads();
  }
  if (t<nb) bsum[t]=sh[t]-v;
  if (t==511) *total = sh[511];
}
__global__ void k_scanC(int* excl, const int* __restrict__ bsum, int n, int* cur){
  int i = blockIdx.x*256+threadIdx.x; if(i>=n) return;
  int v = excl[i]+bsum[blockIdx.x]; excl[i]=v; cur[i]=v;
}
__global__ void k_fill(const int* __restrict__ ei, int E, const float* __restrict__ dinv,
                       int* curf, int* curb, int* sf, float* wf, int* sb, float* wb){
  int e = blockIdx.x*256+threadIdx.x; if(e>=E) return;
  int r = ei[e], c = ei[E+e];
  float w = WEDGE * dinv[r]*dinv[c];
  int pf = atomicAdd(&curf[r],1); sf[pf]=c; wf[pf]=w;
  int pb = atomicAdd(&curb[c],1); sb[pb]=r; wb[pb]=w;
}

// ---------------- layer 1 (scalar cheb) ----------------
__global__ void k_sprop(const float* __restrict__ t1f, const float* __restrict__ t0f, float* df,
                        const float* __restrict__ t1b, const float* __restrict__ t0b, float* db,
                        const int* __restrict__ offf, const int* __restrict__ sfa, const float* __restrict__ wfa,
                        const int* __restrict__ offb, const int* __restrict__ sba, const float* __restrict__ wba,
                        int N){
  int i = blockIdx.x*256+threadIdx.x;
  int dir = 0; if (i >= N){ i -= N; dir = 1; }
  if (i >= N) return;
  const float* t1; const float* t0; float* d; const int* off; const int* s; const float* w;
  if (dir==0){ t1=t1f; t0=t0f; d=df; off=offf; s=sfa; w=wfa; }
  else       { t1=t1b; t0=t0b; d=db; off=offb; s=sba; w=wba; }
  float a = WLOOP * t1[i];
  int e1 = off[i+1];
  for (int e=off[i]; e<e1; ++e) a += w[e]*t1[s[e]];
  d[i] = t0 ? (2.f*a - t0[i]) : a;
}

__global__ void k_expand(const float* __restrict__ x,
   const float* __restrict__ cf1, const float* __restrict__ cf2, const float* __restrict__ cf3, const float* __restrict__ cf4,
   const float* __restrict__ cb1, const float* __restrict__ cb2, const float* __restrict__ cb3, const float* __restrict__ cb4,
   const float* __restrict__ W1f, const float* __restrict__ b1f,
   const float* __restrict__ W1b, const float* __restrict__ b1b,
   u16* __restrict__ T, int N){
  __shared__ float swf[640], swb[640], sbias[128];
  int tid = threadIdx.x;
  for (int i=tid;i<640;i+=256){ swf[i]=W1f[i]; swb[i]=W1b[i]; }
  if (tid<128) sbias[tid]=b1f[tid]+b1b[tid];
  __syncthreads();
  int j = tid & 127; int n = blockIdx.x*2 + (tid>>7);
  if (n>=N) return;
  float xx = x[n];
  float acc = sbias[j] + xx*(swf[j]+swb[j]);
  acc += cf1[n]*swf[128+j]; acc += cf2[n]*swf[256+j]; acc += cf3[n]*swf[384+j]; acc += cf4[n]*swf[512+j];
  acc += cb1[n]*swb[128+j]; acc += cb2[n]*swb[256+j]; acc += cb3[n]*swb[384+j]; acc += cb4[n]*swb[512+j];
  T[(size_t)n*1152 + j] = f2bf(fmaxf(acc,0.f));
}

// ---------------- layer 2 vector props (bf16 rows, fp32 accum) ----------------
__global__ void k_vprop(u16* __restrict__ T,
   const int* __restrict__ offf, const int* __restrict__ sfa, const float* __restrict__ wfa,
   const int* __restrict__ offb, const int* __restrict__ sba, const float* __restrict__ wba,
   int ssf, int dsf, int psf, int ssb, int dsb, int psb, int N){
  int gid = blockIdx.x*256 + threadIdx.x;
  int wid = gid>>6, l = threadIdx.x & 63;
  int dir = 0; if (wid >= N){ wid -= N; dir = 1; }
  if (wid >= N) return;
  const int* off; const int* s; const float* w; int ss,ds,ps;
  if (!dir){ off=offf;s=sfa;w=wfa;ss=ssf;ds=dsf;ps=psf; }
  else     { off=offb;s=sba;w=wba;ss=ssb;ds=dsb;ps=psb; }
  u32 u = *(const u32*)(T + ((size_t)wid*1152 + ss*128) + 2*l);
  float a0 = WLOOP*bf2f(u&0xffff), a1 = WLOOP*bf2f(u>>16);
  int e1 = off[wid+1];
  for (int e=off[wid]; e<e1; ++e){
    int sn = s[e]; float we = w[e];
    u32 ug = *(const u32*)(T + ((size_t)sn*1152 + ss*128) + 2*l);
    a0 += we*bf2f(ug&0xffff); a1 += we*bf2f(ug>>16);
  }
  float r0=a0, r1=a1;
  if (ps >= 0){
    u32 up = *(const u32*)(T + ((size_t)wid*1152 + ps*128) + 2*l);
    r0 = 2.f*a0 - bf2f(up&0xffff); r1 = 2.f*a1 - bf2f(up>>16);
  }
  *(u32*)(T + ((size_t)wid*1152 + ds*128) + 2*l) = ((u32)f2bf(r1)<<16) | (u32)f2bf(r0);
}

// ---------------- weight prep ----------------
__global__ void k_wprep(const float* __restrict__ W2f, const float* __restrict__ W2b,
                        const float* __restrict__ b2f, const float* __restrict__ b2b,
                        u16* __restrict__ Wt, float* __restrict__ bias2){
  int i = blockIdx.x*256+threadIdx.x;
  if (i < 512) bias2[i] = b2f[i]+b2b[i];
  if (i >= 512*1152) return;
  int j = i/1152, kc = i - j*1152;
  int s2 = kc>>7, c = kc&127;
  float v;
  if (s2==0)      v = W2f[c*512+j] + W2b[c*512+j];
  else if (s2<5)  v = W2f[(s2*128+c)*512 + j];
  else            v = W2b[((s2-4)*128+c)*512 + j];
  Wt[i] = f2bf(v);
}

// ---------------- pooled GEMM: T[M x 1152] @ Wt^T -> relu -> segment-sum ----------------
// BM=128, BN=512, BK=32, 8 waves. Row-major LDS tiles with (row>>1)&3 chunk XOR-swizzle
// (both-sides: pre-swizzled global source + swizzled fragment read -> <=2-way banks).
// Staging coalesced: wave reads 16 aligned 64B lines per global_load_lds.
// Schedule: counted vmcnt(5) + 2 raw s_barrier per K-step (T3/T4), setprio (T5).
__global__ __launch_bounds__(512, 2) void k_gemm(const u16* __restrict__ T, const u16* __restrict__ Wt,
                        const float* __restrict__ bias2, const int* __restrict__ batch,
                        float* __restrict__ outp, int Mvalid){
  __shared__ u16 Al[2][128*32];     // 8KB per buf, row-major [row][32]
  __shared__ u16 Bl[2][512*32];     // 32KB per buf, row-major [row][32]
  int bm = blockIdx.x;
  int tid = threadIdx.x, w = tid>>6, l = tid&63;
  int wr = w>>2, wc = w&3;          // wave grid 2 x 4 -> per-wave 64 rows x 128 cols
  int hi = l>>4, lo = l&15;

  f32x4 acc[4][8];
  #pragma unroll
  for (int m=0;m<4;m++)
    #pragma unroll
    for (int n=0;n<8;n++){ acc[m][n][0]=0.f; acc[m][n][1]=0.f; acc[m][n][2]=0.f; acc[m][n][3]=0.f; }

  // staging: thread -> (row = tid>>2, lds chunk slot = tid&3); source chunk pre-swizzled
  int sr = tid>>2, sp = tid&3;
  int csrc = ((sp ^ ((sr>>1)&3)))*8;                       // swizzled k-chunk in source
  const u16* asrc = T  + (size_t)(bm*128 + sr)*1152 + csrc;
  const u16* bsrc = Wt + (size_t)sr*1152 + csrc;           // + i*128*1152
  const int adst = tid*8;                                  // u16 idx: linear, = wave base + lane*16B

  // fragment read bases: row-major + same XOR on read side
  int rsw = (hi ^ ((lo>>1)&3))*8;
  const int abase = (wr*64 + lo)*32 + rsw;                 // + m*512
  const int bbase = (wc*128 + lo)*32 + rsw;                // + n*512

  #define STAGE(buf, kk) do { \
    async16(&Al[buf][adst], asrc + (kk)); \
    _Pragma("unroll") \
    for (int i_=0;i_<4;i_++) async16(&Bl[buf][i_*4096 + adst], bsrc + (size_t)i_*147456 + (kk)); \
  } while(0)

  STAGE(0, 0);
  for (int t=0; t<36; ++t){                                 // K = 1152 = 36*32
    int cur = t & 1;
    if (t < 35){
      STAGE(cur^1, (t+1)*32);
      asm volatile("s_waitcnt vmcnt(5)" ::: "memory");      // stage(t) landed, stage(t+1) in flight
    } else {
      asm volatile("s_waitcnt vmcnt(0)" ::: "memory");
    }
    asm volatile("s_barrier" ::: "memory");                 // tile t resident for all waves
    const u16* Ab = Al[cur]; const u16* Bb = Bl[cur];
    bf16x8 af[4], bfr[8];
    #pragma unroll
    for (int m=0;m<4;m++) af[m] = *(const bf16x8*)&Ab[abase + m*512];
    #pragma unroll
    for (int n=0;n<8;n++) bfr[n] = *(const bf16x8*)&Bb[bbase + n*512];
    __builtin_amdgcn_s_setprio(1);
    #pragma unroll
    for (int m=0;m<4;m++)
      #pragma unroll
      for (int n=0;n<8;n++)
        acc[m][n] = __builtin_amdgcn_mfma_f32_16x16x32_bf16(af[m], bfr[n], acc[m][n], 0, 0, 0);
    __builtin_amdgcn_s_setprio(0);
    asm volatile("s_barrier" ::: "memory");                 // reads done -> next stage may overwrite
  }
  #undef STAGE

  // epilogue: bias + relu + pooled segment-sum (batch sorted -> run-length over 16 rows)
  int bg[16];
  #pragma unroll
  for (int m=0;m<4;m++)
    #pragma unroll
    for (int j2=0;j2<4;j2++){
      int row = bm*128 + wr*64 + m*16 + hi*4 + j2;
      bg[m*4+j2] = (row < Mvalid) ? batch[row] : -1;
    }
  #pragma unroll
  for (int n=0;n<8;n++){
    int col = wc*128 + n*16 + lo;
    float bc = bias2[col];
    int cg2 = -1; float ssum = 0.f;
    #pragma unroll
    for (int idx=0; idx<16; idx++){
      int g = bg[idx];
      if (g >= 0){
        float val = fmaxf(acc[idx>>2][n][idx&3] + bc, 0.f);
        if (g != cg2){ if (cg2 >= 0) atomicAdd(&outp[(cg2<<9) + col], ssum); cg2 = g; ssum = 0.f; }
        ssum += val;
      }
    }
    if (cg2 >= 0) atomicAdd(&outp[(cg2<<9) + col], ssum);
  }
}

// per-block LDS histogram: ~200 global atomics total instead of 100k
__global__ void k_count(const int* __restrict__ batch, int* cg, int N){
  __shared__ int sh[64];
  int t = threadIdx.x;
  if (t < 64) sh[t] = 0;
  __syncthreads();
  int base = blockIdx.x*1024;
  #pragma unroll
  for (int i = base + t; i < base + 1024; i += 256){
    if (i < N) atomicAdd(&sh[batch[i]], 1);
  }
  __syncthreads();
  if (t < 64){ int v = sh[t]; if (v) atomicAdd(&cg[t], v); }
}

__global__ void k_div(float* out, const int* __restrict__ cg, int total){
  int i = blockIdx.x*256+threadIdx.x; if (i>=total) return;
  int g = i>>9; out[i] /= fmaxf((float)cg[g], 1.f);
}

extern "C" void kernel_launch(void* const* d_in, const int* in_sizes, int n_in,
                              void* d_out, int out_size, void* d_ws, size_t ws_size,
                              hipStream_t stream) {
  const float* x   = (const float*)d_in[0];
  const int*   ei  = (const int*)d_in[1];
  const int*   bat = (const int*)d_in[2];
  const float* W1f = (const float*)d_in[3];
  const float* b1f = (const float*)d_in[4];
  const float* W1b = (const float*)d_in[5];
  const float* b1b = (const float*)d_in[6];
  const float* W2f = (const float*)d_in[7];
  const float* b2f = (const float*)d_in[8];
  const float* W2b = (const float*)d_in[9];
  const float* b2b = (const float*)d_in[10];

  const int N  = in_sizes[0];
  const int E  = in_sizes[1] / 2;
  const int NP = ((N + 127)/128)*128;

  // ---- ws layout ----
  size_t p = 0;
  auto A = [&](size_t sz){ size_t r = p; p += (sz + 255) & ~(size_t)255; return r; };
  size_t o_cnt  = A(2*(size_t)N*4);          // cnt_f | cnt_b
  size_t o_offf = A(((size_t)N+1)*4);
  size_t o_offb = A(((size_t)N+1)*4);
  size_t o_curf = A((size_t)N*4);
  size_t o_curb = A((size_t)N*4);
  size_t o_bsum = A(512*4);
  size_t o_dinv = A((size_t)N*4);
  size_t o_csf  = A((size_t)E*4);
  size_t o_cwf  = A((size_t)E*4);
  size_t o_csb  = A((size_t)E*4);
  size_t o_cwb  = A((size_t)E*4);
  size_t o_cf   = A(8*(size_t)N*4);          // cf1..4, cb1..4
  size_t o_Wt   = A((size_t)512*1152*2);
  size_t o_b2   = A(512*4);
  size_t o_cg   = A(64*4);
  size_t o_T    = A((size_t)NP*1152*2);
  if (p > ws_size) return;  // ws too small: bail (visible as validation failure)

  char* ws = (char*)d_ws;
  int*   cnt_f = (int*)(ws + o_cnt);
  int*   cnt_b = cnt_f + N;
  int*   off_f = (int*)(ws + o_offf);
  int*   off_b = (int*)(ws + o_offb);
  int*   cur_f = (int*)(ws + o_curf);
  int*   cur_b = (int*)(ws + o_curb);
  int*   bsum  = (int*)(ws + o_bsum);
  float* dinv  = (float*)(ws + o_dinv);
  int*   csf   = (int*)(ws + o_csf);
  float* cwf   = (float*)(ws + o_cwf);
  int*   csb   = (int*)(ws + o_csb);
  float* cwb   = (float*)(ws + o_cwb);
  float* cf1   = (float*)(ws + o_cf);
  float* cf2   = cf1 + N; float* cf3 = cf2 + N; float* cf4 = cf3 + N;
  float* cb1   = cf4 + N; float* cb2 = cb1 + N; float* cb3 = cb2 + N; float* cb4 = cb3 + N;
  u16*   Wt    = (u16*)(ws + o_Wt);
  float* bias2 = (float*)(ws + o_b2);
  int*   cg    = (int*)(ws + o_cg);
  u16*   T     = (u16*)(ws + o_T);
  float* outp  = (float*)d_out;

  const int nbN = (N + 255)/256;
  const int nbE = (E + 255)/256;
  const int nb2N = (2*N + 255)/256;

  // zero-init accumulators + T pad rows
  hipMemsetAsync(cnt_f, 0, 2*(size_t)N*4, stream);
  hipMemsetAsync(cg, 0, 64*4, stream);
  hipMemsetAsync(d_out, 0, (size_t)out_size*4, stream);
  if (NP > N) hipMemsetAsync(T + (size_t)N*1152, 0, (size_t)(NP-N)*1152*2, stream);

  // graph prep
  k_hist<<<nbE,256,0,stream>>>(ei, E, cnt_f, cnt_b);
  k_dinv<<<nbN,256,0,stream>>>(cnt_f, dinv, N);
  k_scanA<<<nbN,256,0,stream>>>(cnt_f, off_f, bsum, N);
  k_scanB<<<1,512,0,stream>>>(bsum, nbN, off_f + N);
  k_scanC<<<nbN,256,0,stream>>>(off_f, bsum, N, cur_f);
  k_scanA<<<nbN,256,0,stream>>>(cnt_b, off_b, bsum, N);
  k_scanB<<<1,512,0,stream>>>(bsum, nbN, off_b + N);
  k_scanC<<<nbN,256,0,stream>>>(off_b, bsum, N, cur_b);
  k_fill<<<nbE,256,0,stream>>>(ei, E, dinv, cur_f, cur_b, csf, cwf, csb, cwb);

  // layer 1 scalar chebyshev
  k_sprop<<<nb2N,256,0,stream>>>(x,   nullptr, cf1,  x,   nullptr, cb1, off_f,csf,cwf, off_b,csb,cwb, N);
  k_sprop<<<nb2N,256,0,stream>>>(cf1, x,       cf2,  cb1, x,       cb2, off_f,csf,cwf, off_b,csb,cwb, N);
  k_sprop<<<nb2N,256,0,stream>>>(cf2, cf1,     cf3,  cb2, cb1,     cb3, off_f,csf,cwf, off_b,csb,cwb, N);
  k_sprop<<<nb2N,256,0,stream>>>(cf3, cf2,     cf4,  cb3, cb2,     cb4, off_f,csf,cwf, off_b,csb,cwb, N);
  k_expand<<<(N+1)/2,256,0,stream>>>(x, cf1,cf2,cf3,cf4, cb1,cb2,cb3,cb4, W1f,b1f,W1b,b1b, T, N);

  // weights for fused GEMM
  k_wprep<<<(512*1152+255)/256,256,0,stream>>>(W2f, W2b, b2f, b2b, Wt, bias2);

  // layer 2 vector chebyshev: slots 0=h, 1..4=fwd, 5..8=bwd
  const int vb = (2*N*64 + 255)/256;
  k_vprop<<<vb,256,0,stream>>>(T, off_f,csf,cwf, off_b,csb,cwb, 0,1,-1, 0,5,-1, N);
  k_vprop<<<vb,256,0,stream>>>(T, off_f,csf,cwf, off_b,csb,cwb, 1,2, 0, 5,6, 0, N);
  k_vprop<<<vb,256,0,stream>>>(T, off_f,csf,cwf, off_b,csb,cwb, 2,3, 1, 6,7, 5, N);
  k_vprop<<<vb,256,0,stream>>>(T, off_f,csf,cwf, off_b,csb,cwb, 3,4, 2, 7,8, 6, N);

  // pooled GEMM + mean
  k_count<<<(N+1023)/1024,256,0,stream>>>(bat, cg, N);
  k_gemm<<<NP/128,512,0,stream>>>(T, Wt, bias2, bat, outp, N);
  k_div<<<(out_size+255)/256,256,0,stream>>>(outp, cg, out_size);
}

// Round 6
// 714.233 us; speedup vs baseline: 1.4169x; 1.1851x over previous
//
#include <hip/hip_runtime.h>
#include <hip/hip_bf16.h>

typedef unsigned short u16;
typedef unsigned int u32;
typedef __attribute__((ext_vector_type(4))) float f32x4;
typedef __attribute__((ext_vector_type(8))) short bf16x8;

#define WLOOP (2.0f/3.0f - 1.0f)      /* -1/3 */
#define WEDGE (-(2.0f/3.0f))          /* -(2/lambda_max) */

__device__ __forceinline__ float bf2f(u16 h){ u32 u = ((u32)h)<<16; float f; __builtin_memcpy(&f,&u,4); return f; }
__device__ __forceinline__ u16 f2bf(float f){ u32 u; __builtin_memcpy(&u,&f,4); u32 r = u + 0x7fffu + ((u>>16)&1u); return (u16)(r>>16); }

__device__ __forceinline__ void async16(u16* lds, const u16* g){
  __builtin_amdgcn_global_load_lds((const __attribute__((address_space(1))) u32*)g,
                                   (__attribute__((address_space(3))) u32*)lds, 16, 0, 0);
}

// ---------------- graph prep ----------------
__global__ void k_hist(const int* __restrict__ ei, int E, int* cntf, int* cntb){
  int e = blockIdx.x*256 + threadIdx.x; if (e>=E) return;
  atomicAdd(&cntf[ei[e]],1); atomicAdd(&cntb[ei[E+e]],1);
}
__global__ void k_dinv(const int* __restrict__ cntf, float* dinv, int N){
  int n = blockIdx.x*256+threadIdx.x; if(n>=N) return;
  int d = cntf[n]; dinv[n] = d>0 ? rsqrtf((float)d) : 0.f;
}
__global__ void k_scanA(const int* __restrict__ cnt, int* excl, int* bsum, int n){
  __shared__ int sh[256]; int i = blockIdx.x*256+threadIdx.x;
  int v = (i<n)? cnt[i]:0; sh[threadIdx.x]=v; __syncthreads();
  for (int off=1; off<256; off<<=1){
    int t = (threadIdx.x>=off)? sh[threadIdx.x-off]:0; __syncthreads();
    sh[threadIdx.x]+=t; __syncthreads();
  }
  if (i<n) excl[i]=sh[threadIdx.x]-v;
  if (threadIdx.x==255) bsum[blockIdx.x]=sh[255];
}
__global__ void k_scanB(int* bsum, int nb, int* total){
  __shared__ int sh[512]; int t = threadIdx.x;
  int v = (t<nb)? bsum[t]:0; sh[t]=v; __syncthreads();
  for(int off=1; off<512; off<<=1){
    int a = (t>=off)? sh[t-off]:0; __syncthreads();
    sh[t]+=a; __syncthreads();
  }
  if (t<nb) bsum[t]=sh[t]-v;
  if (t==511) *total = sh[511];
}
__global__ void k_scanC(int* excl, const int* __restrict__ bsum, int n, int* cur){
  int i = blockIdx.x*256+threadIdx.x; if(i>=n) return;
  int v = excl[i]+bsum[blockIdx.x]; excl[i]=v; cur[i]=v;
}
__global__ void k_fill(const int* __restrict__ ei, int E, const float* __restrict__ dinv,
                       int* curf, int* curb, int* sf, float* wf, int* sb, float* wb){
  int e = blockIdx.x*256+threadIdx.x; if(e>=E) return;
  int r = ei[e], c = ei[E+e];
  float w = WEDGE * dinv[r]*dinv[c];
  int pf = atomicAdd(&curf[r],1); sf[pf]=c; wf[pf]=w;
  int pb = atomicAdd(&curb[c],1); sb[pb]=r; wb[pb]=w;
}

// ---------------- layer 1 (scalar cheb), 4-way unrolled gathers ----------------
__global__ void k_sprop(const float* __restrict__ t1f, const float* __restrict__ t0f, float* df,
                        const float* __restrict__ t1b, const float* __restrict__ t0b, float* db,
                        const int* __restrict__ offf, const int* __restrict__ sfa, const float* __restrict__ wfa,
                        const int* __restrict__ offb, const int* __restrict__ sba, const float* __restrict__ wba,
                        int N){
  int i = blockIdx.x*256+threadIdx.x;
  int dir = 0; if (i >= N){ i -= N; dir = 1; }
  if (i >= N) return;
  const float* t1; const float* t0; float* d; const int* off; const int* s; const float* w;
  if (dir==0){ t1=t1f; t0=t0f; d=df; off=offf; s=sfa; w=wfa; }
  else       { t1=t1b; t0=t0b; d=db; off=offb; s=sba; w=wba; }
  float a = WLOOP * t1[i];
  int e = off[i], e1 = off[i+1];
  for (; e+4<=e1; e+=4){
    int s0=s[e], s1=s[e+1], s2=s[e+2], s3=s[e+3];
    float v0=t1[s0], v1=t1[s1], v2=t1[s2], v3=t1[s3];
    a += w[e]*v0 + w[e+1]*v1 + w[e+2]*v2 + w[e+3]*v3;
  }
  for (; e<e1; ++e) a += w[e]*t1[s[e]];
  d[i] = t0 ? (2.f*a - t0[i]) : a;
}

__global__ void k_expand(const float* __restrict__ x,
   const float* __restrict__ cf1, const float* __restrict__ cf2, const float* __restrict__ cf3, const float* __restrict__ cf4,
   const float* __restrict__ cb1, const float* __restrict__ cb2, const float* __restrict__ cb3, const float* __restrict__ cb4,
   const float* __restrict__ W1f, const float* __restrict__ b1f,
   const float* __restrict__ W1b, const float* __restrict__ b1b,
   u16* __restrict__ T, int N){
  __shared__ float swf[640], swb[640], sbias[128];
  int tid = threadIdx.x;
  for (int i=tid;i<640;i+=256){ swf[i]=W1f[i]; swb[i]=W1b[i]; }
  if (tid<128) sbias[tid]=b1f[tid]+b1b[tid];
  __syncthreads();
  int j = tid & 127; int n = blockIdx.x*2 + (tid>>7);
  if (n>=N) return;
  float xx = x[n];
  float acc = sbias[j] + xx*(swf[j]+swb[j]);
  acc += cf1[n]*swf[128+j]; acc += cf2[n]*swf[256+j]; acc += cf3[n]*swf[384+j]; acc += cf4[n]*swf[512+j];
  acc += cb1[n]*swb[128+j]; acc += cb2[n]*swb[256+j]; acc += cb3[n]*swb[384+j]; acc += cb4[n]*swb[512+j];
  T[(size_t)n*1152 + j] = f2bf(fmaxf(acc,0.f));
}

// ---------------- layer 2 vector props (bf16 rows, fp32 accum), 4-way unrolled ----------------
__global__ void k_vprop(u16* __restrict__ T,
   const int* __restrict__ offf, const int* __restrict__ sfa, const float* __restrict__ wfa,
   const int* __restrict__ offb, const int* __restrict__ sba, const float* __restrict__ wba,
   int ssf, int dsf, int psf, int ssb, int dsb, int psb, int N){
  int gid = blockIdx.x*256 + threadIdx.x;
  int wid = gid>>6, l = threadIdx.x & 63;
  int dir = 0; if (wid >= N){ wid -= N; dir = 1; }
  if (wid >= N) return;
  const int* off; const int* s; const float* w; int ss,ds,ps;
  if (!dir){ off=offf;s=sfa;w=wfa;ss=ssf;ds=dsf;ps=psf; }
  else     { off=offb;s=sba;w=wba;ss=ssb;ds=dsb;ps=psb; }
  const u16* Tss = T + (size_t)ss*128 + 2*l;                  // + row*1152
  u32 u = *(const u32*)(Tss + (size_t)wid*1152);
  float a0 = WLOOP*bf2f(u&0xffff), a1 = WLOOP*bf2f(u>>16);
  int e = off[wid], e1 = off[wid+1];
  for (; e+4<=e1; e+=4){
    int s0=s[e], s1=s[e+1], s2=s[e+2], s3=s[e+3];
    float w0=w[e], w1=w[e+1], w2=w[e+2], w3=w[e+3];
    u32 g0 = *(const u32*)(Tss + (size_t)s0*1152);
    u32 g1 = *(const u32*)(Tss + (size_t)s1*1152);
    u32 g2 = *(const u32*)(Tss + (size_t)s2*1152);
    u32 g3 = *(const u32*)(Tss + (size_t)s3*1152);
    a0 += w0*bf2f(g0&0xffff) + w1*bf2f(g1&0xffff) + w2*bf2f(g2&0xffff) + w3*bf2f(g3&0xffff);
    a1 += w0*bf2f(g0>>16)    + w1*bf2f(g1>>16)    + w2*bf2f(g2>>16)    + w3*bf2f(g3>>16);
  }
  for (; e<e1; ++e){
    int sn = s[e]; float we = w[e];
    u32 ug = *(const u32*)(Tss + (size_t)sn*1152);
    a0 += we*bf2f(ug&0xffff); a1 += we*bf2f(ug>>16);
  }
  float r0=a0, r1=a1;
  if (ps >= 0){
    u32 up = *(const u32*)(T + ((size_t)wid*1152 + ps*128) + 2*l);
    r0 = 2.f*a0 - bf2f(up&0xffff); r1 = 2.f*a1 - bf2f(up>>16);
  }
  *(u32*)(T + ((size_t)wid*1152 + ds*128) + 2*l) = ((u32)f2bf(r1)<<16) | (u32)f2bf(r0);
}

// ---------------- weight prep ----------------
__global__ void k_wprep(const float* __restrict__ W2f, const float* __restrict__ W2b,
                        const float* __restrict__ b2f, const float* __restrict__ b2b,
                        u16* __restrict__ Wt, float* __restrict__ bias2){
  int i = blockIdx.x*256+threadIdx.x;
  if (i < 512) bias2[i] = b2f[i]+b2b[i];
  if (i >= 512*1152) return;
  int j = i/1152, kc = i - j*1152;
  int s2 = kc>>7, c = kc&127;
  float v;
  if (s2==0)      v = W2f[c*512+j] + W2b[c*512+j];
  else if (s2<5)  v = W2f[(s2*128+c)*512 + j];
  else            v = W2b[((s2-4)*128+c)*512 + j];
  Wt[i] = f2bf(v);
}

// ---------------- pooled GEMM: T[M x 1152] @ Wt^T -> relu -> segment-sum ----------------
// BM=128, BN=512, BK=32, 8 waves, 64x128 per wave (acc 128 regs -> 1 block/CU fixed).
// Triple-buffered LDS (120KB), depth-2 prefetch: stage(t+2) issued, vmcnt(10) waits
// stage(t) -> each stage has ~2 iterations to cover HBM latency. Both-sides chunk
// XOR-swizzle, coalesced staging (16x64B lines/wave), raw s_barrier x2, setprio.
__global__ __launch_bounds__(512, 2) void k_gemm(const u16* __restrict__ T, const u16* __restrict__ Wt,
                        const float* __restrict__ bias2, const int* __restrict__ batch,
                        float* __restrict__ outp, int Mvalid){
  __shared__ u16 Al[3][128*32];     // 8KB per buf
  __shared__ u16 Bl[3][512*32];     // 32KB per buf
  int bm = blockIdx.x;
  int tid = threadIdx.x, w = tid>>6, l = tid&63;
  int wr = w>>2, wc = w&3;          // wave grid 2 x 4 -> per-wave 64 rows x 128 cols
  int hi = l>>4, lo = l&15;

  f32x4 acc[4][8];
  #pragma unroll
  for (int m=0;m<4;m++)
    #pragma unroll
    for (int n=0;n<8;n++){ acc[m][n][0]=0.f; acc[m][n][1]=0.f; acc[m][n][2]=0.f; acc[m][n][3]=0.f; }

  // staging: thread -> (row = tid>>2, lds chunk slot = tid&3); source chunk pre-swizzled
  int sr = tid>>2, sp = tid&3;
  int csrc = ((sp ^ ((sr>>1)&3)))*8;                       // swizzled k-chunk in source
  const u16* asrc = T  + (size_t)(bm*128 + sr)*1152 + csrc;
  const u16* bsrc = Wt + (size_t)sr*1152 + csrc;           // + i*128*1152
  const int adst = tid*8;                                  // u16 idx: linear, wave base + lane*16B

  // fragment read bases: row-major + same XOR on read side
  int rsw = (hi ^ ((lo>>1)&3))*8;
  const int abase = (wr*64 + lo)*32 + rsw;                 // + m*512
  const int bbase = (wc*128 + lo)*32 + rsw;                // + n*512

  #define STAGE(buf, kk) do { \
    async16(&Al[buf][adst], asrc + (kk)); \
    _Pragma("unroll") \
    for (int i_=0;i_<4;i_++) async16(&Bl[buf][i_*4096 + adst], bsrc + (size_t)i_*147456 + (kk)); \
  } while(0)

  STAGE(0, 0);
  STAGE(1, 32);
  int cw = 0, cs = 2;                                       // compute buf, stage buf (t+2)
  for (int t=0; t<36; ++t){                                 // K = 1152 = 36*32
    if (t <= 33){
      STAGE(cs, (t+2)*32);
      asm volatile("s_waitcnt vmcnt(10)" ::: "memory");     // stage(t) landed; t+1,t+2 in flight
    } else if (t == 34){
      asm volatile("s_waitcnt vmcnt(5)" ::: "memory");      // stage(34) landed; 35 in flight
    } else {
      asm volatile("s_waitcnt vmcnt(0)" ::: "memory");
    }
    asm volatile("s_barrier" ::: "memory");                 // tile t resident for all waves
    const u16* Ab = Al[cw]; const u16* Bb = Bl[cw];
    bf16x8 af[4], bfr[8];
    #pragma unroll
    for (int m=0;m<4;m++) af[m] = *(const bf16x8*)&Ab[abase + m*512];
    #pragma unroll
    for (int n=0;n<8;n++) bfr[n] = *(const bf16x8*)&Bb[bbase + n*512];
    __builtin_amdgcn_s_setprio(1);
    #pragma unroll
    for (int m=0;m<4;m++)
      #pragma unroll
      for (int n=0;n<8;n++)
        acc[m][n] = __builtin_amdgcn_mfma_f32_16x16x32_bf16(af[m], bfr[n], acc[m][n], 0, 0, 0);
    __builtin_amdgcn_s_setprio(0);
    asm volatile("s_barrier" ::: "memory");                 // reads of buf cw done -> re-stageable
    cw = (cw==2)?0:cw+1; cs = (cs==2)?0:cs+1;
  }
  #undef STAGE

  // epilogue: bias + relu + pooled segment-sum (batch sorted -> run-length over 16 rows)
  int bg[16];
  #pragma unroll
  for (int m=0;m<4;m++)
    #pragma unroll
    for (int j2=0;j2<4;j2++){
      int row = bm*128 + wr*64 + m*16 + hi*4 + j2;
      bg[m*4+j2] = (row < Mvalid) ? batch[row] : -1;
    }
  #pragma unroll
  for (int n=0;n<8;n++){
    int col = wc*128 + n*16 + lo;
    float bc = bias2[col];
    int cg2 = -1; float ssum = 0.f;
    #pragma unroll
    for (int idx=0; idx<16; idx++){
      int g = bg[idx];
      if (g >= 0){
        float val = fmaxf(acc[idx>>2][n][idx&3] + bc, 0.f);
        if (g != cg2){ if (cg2 >= 0) atomicAdd(&outp[(cg2<<9) + col], ssum); cg2 = g; ssum = 0.f; }
        ssum += val;
      }
    }
    if (cg2 >= 0) atomicAdd(&outp[(cg2<<9) + col], ssum);
  }
}

// per-block LDS histogram: ~200 global atomics total instead of 100k
__global__ void k_count(const int* __restrict__ batch, int* cg, int N){
  __shared__ int sh[64];
  int t = threadIdx.x;
  if (t < 64) sh[t] = 0;
  __syncthreads();
  int base = blockIdx.x*1024;
  #pragma unroll
  for (int i = base + t; i < base + 1024; i += 256){
    if (i < N) atomicAdd(&sh[batch[i]], 1);
  }
  __syncthreads();
  if (t < 64){ int v = sh[t]; if (v) atomicAdd(&cg[t], v); }
}

__global__ void k_div(float* out, const int* __restrict__ cg, int total){
  int i = blockIdx.x*256+threadIdx.x; if (i>=total) return;
  int g = i>>9; out[i] /= fmaxf((float)cg[g], 1.f);
}

extern "C" void kernel_launch(void* const* d_in, const int* in_sizes, int n_in,
                              void* d_out, int out_size, void* d_ws, size_t ws_size,
                              hipStream_t stream) {
  const float* x   = (const float*)d_in[0];
  const int*   ei  = (const int*)d_in[1];
  const int*   bat = (const int*)d_in[2];
  const float* W1f = (const float*)d_in[3];
  const float* b1f = (const float*)d_in[4];
  const float* W1b = (const float*)d_in[5];
  const float* b1b = (const float*)d_in[6];
  const float* W2f = (const float*)d_in[7];
  const float* b2f = (const float*)d_in[8];
  const float* W2b = (const float*)d_in[9];
  const float* b2b = (const float*)d_in[10];

  const int N  = in_sizes[0];
  const int E  = in_sizes[1] / 2;
  const int NP = ((N + 127)/128)*128;

  // ---- ws layout ----
  size_t p = 0;
  auto A = [&](size_t sz){ size_t r = p; p += (sz + 255) & ~(size_t)255; return r; };
  size_t o_cnt  = A(2*(size_t)N*4);          // cnt_f | cnt_b
  size_t o_offf = A(((size_t)N+1)*4);
  size_t o_offb = A(((size_t)N+1)*4);
  size_t o_curf = A((size_t)N*4);
  size_t o_curb = A((size_t)N*4);
  size_t o_bsum = A(512*4);
  size_t o_dinv = A((size_t)N*4);
  size_t o_csf  = A((size_t)E*4);
  size_t o_cwf  = A((size_t)E*4);
  size_t o_csb  = A((size_t)E*4);
  size_t o_cwb  = A((size_t)E*4);
  size_t o_cf   = A(8*(size_t)N*4);          // cf1..4, cb1..4
  size_t o_Wt   = A((size_t)512*1152*2);
  size_t o_b2   = A(512*4);
  size_t o_cg   = A(64*4);
  size_t o_T    = A((size_t)NP*1152*2);
  if (p > ws_size) return;  // ws too small: bail (visible as validation failure)

  char* ws = (char*)d_ws;
  int*   cnt_f = (int*)(ws + o_cnt);
  int*   cnt_b = cnt_f + N;
  int*   off_f = (int*)(ws + o_offf);
  int*   off_b = (int*)(ws + o_offb);
  int*   cur_f = (int*)(ws + o_curf);
  int*   cur_b = (int*)(ws + o_curb);
  int*   bsum  = (int*)(ws + o_bsum);
  float* dinv  = (float*)(ws + o_dinv);
  int*   csf   = (int*)(ws + o_csf);
  float* cwf   = (float*)(ws + o_cwf);
  int*   csb   = (int*)(ws + o_csb);
  float* cwb   = (float*)(ws + o_cwb);
  float* cf1   = (float*)(ws + o_cf);
  float* cf2   = cf1 + N; float* cf3 = cf2 + N; float* cf4 = cf3 + N;
  float* cb1   = cf4 + N; float* cb2 = cb1 + N; float* cb3 = cb2 + N; float* cb4 = cb3 + N;
  u16*   Wt    = (u16*)(ws + o_Wt);
  float* bias2 = (float*)(ws + o_b2);
  int*   cg    = (int*)(ws + o_cg);
  u16*   T     = (u16*)(ws + o_T);
  float* outp  = (float*)d_out;

  const int nbN = (N + 255)/256;
  const int nbE = (E + 255)/256;
  const int nb2N = (2*N + 255)/256;

  // zero-init accumulators + T pad rows
  hipMemsetAsync(cnt_f, 0, 2*(size_t)N*4, stream);
  hipMemsetAsync(cg, 0, 64*4, stream);
  hipMemsetAsync(d_out, 0, (size_t)out_size*4, stream);
  if (NP > N) hipMemsetAsync(T + (size_t)N*1152, 0, (size_t)(NP-N)*1152*2, stream);

  // graph prep
  k_hist<<<nbE,256,0,stream>>>(ei, E, cnt_f, cnt_b);
  k_dinv<<<nbN,256,0,stream>>>(cnt_f, dinv, N);
  k_scanA<<<nbN,256,0,stream>>>(cnt_f, off_f, bsum, N);
  k_scanB<<<1,512,0,stream>>>(bsum, nbN, off_f + N);
  k_scanC<<<nbN,256,0,stream>>>(off_f, bsum, N, cur_f);
  k_scanA<<<nbN,256,0,stream>>>(cnt_b, off_b, bsum, N);
  k_scanB<<<1,512,0,stream>>>(bsum, nbN, off_b + N);
  k_scanC<<<nbN,256,0,stream>>>(off_b, bsum, N, cur_b);
  k_fill<<<nbE,256,0,stream>>>(ei, E, dinv, cur_f, cur_b, csf, cwf, csb, cwb);

  // layer 1 scalar chebyshev
  k_sprop<<<nb2N,256,0,stream>>>(x,   nullptr, cf1,  x,   nullptr, cb1, off_f,csf,cwf, off_b,csb,cwb, N);
  k_sprop<<<nb2N,256,0,stream>>>(cf1, x,       cf2,  cb1, x,       cb2, off_f,csf,cwf, off_b,csb,cwb, N);
  k_sprop<<<nb2N,256,0,stream>>>(cf2, cf1,     cf3,  cb2, cb1,     cb3, off_f,csf,cwf, off_b,csb,cwb, N);
  k_sprop<<<nb2N,256,0,stream>>>(cf3, cf2,     cf4,  cb3, cb2,     cb4, off_f,csf,cwf, off_b,csb,cwb, N);
  k_expand<<<(N+1)/2,256,0,stream>>>(x, cf1,cf2,cf3,cf4, cb1,cb2,cb3,cb4, W1f,b1f,W1b,b1b, T, N);

  // weights for fused GEMM
  k_wprep<<<(512*1152+255)/256,256,0,stream>>>(W2f, W2b, b2f, b2b, Wt, bias2);

  // layer 2 vector chebyshev: slots 0=h, 1..4=fwd, 5..8=bwd
  const int vb = (2*N*64 + 255)/256;
  k_vprop<<<vb,256,0,stream>>>(T, off_f,csf,cwf, off_b,csb,cwb, 0,1,-1, 0,5,-1, N);
  k_vprop<<<vb,256,0,stream>>>(T, off_f,csf,cwf, off_b,csb,cwb, 1,2, 0, 5,6, 0, N);
  k_vprop<<<vb,256,0,stream>>>(T, off_f,csf,cwf, off_b,csb,cwb, 2,3, 1, 6,7, 5, N);
  k_vprop<<<vb,256,0,stream>>>(T, off_f,csf,cwf, off_b,csb,cwb, 3,4, 2, 7,8, 6, N);

  // pooled GEMM + mean
  k_count<<<(N+1023)/1024,256,0,stream>>>(bat, cg, N);
  k_gemm<<<NP/128,512,0,stream>>>(T, Wt, bias2, bat, outp, N);
  k_div<<<(out_size+255)/256,256,0,stream>>>(outp, cg, out_size);
}